// Round 3
// baseline (894.361 us; speedup 1.0000x reference)
//
#include <hip/hip_runtime.h>
#include <hip/hip_bf16.h>
#include <cstdint>
#include <cstddef>

typedef __bf16 bf16_t;
typedef __bf16 bf16x8 __attribute__((ext_vector_type(8)));
typedef float  f32x4  __attribute__((ext_vector_type(4)));

#define N_ROWS 65536   // BS*CLIP
#define IN_CH  1024
#define OUT_CH 512
#define T_DIM  512
#define BS_    8192

// ---- async global->LDS, 16B per lane (global_load_lds_dwordx4) ----
__device__ __forceinline__ void async_copy16(const bf16_t* g, bf16_t* l) {
    __builtin_amdgcn_global_load_lds(
        (const __attribute__((address_space(1))) void*)(uintptr_t)(g),
        (__attribute__((address_space(3))) void*)(uintptr_t)(l),
        16, 0, 0);
}

// ---- fp32 -> bf16 pack, 8 elems/thread ----
__global__ __launch_bounds__(256)
void cvt_f32_bf16(const float* __restrict__ in, bf16_t* __restrict__ out, long n8) {
    long idx = (long)blockIdx.x * 256 + threadIdx.x;
    if (idx >= n8) return;
    const float4* p = (const float4*)(in + idx * 8);
    float4 u = p[0], v = p[1];
    bf16x8 o;
    o[0] = (__bf16)u.x; o[1] = (__bf16)u.y; o[2] = (__bf16)u.z; o[3] = (__bf16)u.w;
    o[4] = (__bf16)v.x; o[5] = (__bf16)v.y; o[6] = (__bf16)v.z; o[7] = (__bf16)v.w;
    *(bf16x8*)(out + idx * 8) = o;
}

// ---- batched cvt for t, W_qkv, W_t, W_out (one launch) ----
__global__ __launch_bounds__(256)
void cvt_multi(const float* __restrict__ s0, bf16_t* __restrict__ d0, long n0,
               const float* __restrict__ s1, bf16_t* __restrict__ d1, long n1,
               const float* __restrict__ s2, bf16_t* __restrict__ d2, long n2,
               const float* __restrict__ s3, bf16_t* __restrict__ d3, long n3)
{
    long idx = (long)blockIdx.x * 256 + threadIdx.x;
    const float* s; bf16_t* d;
    if (idx < n0)                { s = s0; d = d0; }
    else if ((idx -= n0) < n1)   { s = s1; d = d1; }
    else if ((idx -= n1) < n2)   { s = s2; d = d2; }
    else if ((idx -= n2) < n3)   { s = s3; d = d3; }
    else return;
    const float4* p = (const float4*)(s + idx * 8);
    float4 u = p[0], v = p[1];
    bf16x8 o;
    o[0] = (__bf16)u.x; o[1] = (__bf16)u.y; o[2] = (__bf16)u.z; o[3] = (__bf16)u.w;
    o[4] = (__bf16)v.x; o[5] = (__bf16)v.y; o[6] = (__bf16)v.z; o[7] = (__bf16)v.w;
    *(bf16x8*)(d + idx * 8) = o;
}

// ---- W_down [512,1024] fp32 -> transposed bf16 [1024,512] ----
__global__ __launch_bounds__(256)
void transpose_cvt(const float* __restrict__ in, bf16_t* __restrict__ out) {
    __shared__ float tile[64][65];
    const int bx = blockIdx.x;
    const int by = blockIdx.y;
    const int tx = threadIdx.x & 63;
    const int ty = threadIdx.x >> 6;
    #pragma unroll
    for (int r = 0; r < 64; r += 4)
        tile[r + ty][tx] = in[(size_t)(by * 64 + r + ty) * 1024 + bx * 64 + tx];
    __syncthreads();
    #pragma unroll
    for (int r = 0; r < 64; r += 4)
        out[(size_t)(bx * 64 + r + ty) * 512 + by * 64 + tx] = (bf16_t)tile[tx][r + ty];
}

// ---- m97-style GEMM with XOR-swizzled LDS: C[M,N] = A[M,K]*B[N,K]^T (+bias) ----
// BIAS_MODE 0: + bias[col]
// BIAS_MODE 1: + bias2[(row>>3)*N + col]  (per-batch row bias, LDS-staged)
// BIAS_MODE 2: + bias[col] + bias2[col]
// BIAS_MODE 3: none
template<int BIAS_MODE, typename CT>
__global__ __launch_bounds__(256, 3)
void gemm_bt(const bf16_t* __restrict__ A, const bf16_t* __restrict__ B,
             CT* __restrict__ C,
             const float* __restrict__ bias,
             const float* __restrict__ bias2,
             int M, int N, int K)
{
    __shared__ __align__(16) bf16_t sA[128 * 32];
    __shared__ __align__(16) bf16_t sB[128 * 32];
    __shared__ float stb[(BIAS_MODE == 1) ? 16 * 132 : 4];

    const int tid  = threadIdx.x;
    const int wave = tid >> 6;
    const int lane = tid & 63;

    const int row0 = blockIdx.y * 128;
    const int col0 = blockIdx.x * 128;

    const int wr = (wave >> 1) * 64;
    const int wc = (wave & 1) * 64;

    // prologue-stage the per-batch bias slice (16 batch rows x 128 cols)
    if constexpr (BIAS_MODE == 1) {
        const int br = tid >> 4;
        const int bc = (tid & 15) * 8;
        const float* bsrc = bias2 + ((size_t)(row0 >> 3) + br) * N + col0 + bc;
        *(float4*)&stb[br * 132 + bc]     = *(const float4*)(bsrc);
        *(float4*)&stb[br * 132 + bc + 4] = *(const float4*)(bsrc + 4);
    }

    f32x4 acc[4][4];
    #pragma unroll
    for (int i = 0; i < 4; ++i)
        #pragma unroll
        for (int j = 0; j < 4; ++j)
            acc[i][j] = (f32x4){0.f, 0.f, 0.f, 0.f};

    // staging: 8 segments of 16 rows; wave w stages segs {2w,2w+1}.
    // source chunk XOR-swizzled by (row&3) so physical chunk p holds logical p^(row&3)
    const int seg0  = wave * 2;
    const int srow  = lane >> 2;
    const int schnk = (((lane & 3) ^ (srow & 3)) * 8);

    const bf16_t* Abase = A + (size_t)row0 * K + (size_t)srow * K + schnk;
    const bf16_t* Bbase = B + (size_t)col0 * K + (size_t)srow * K + schnk;

    const int fr = lane & 15;
    const int hi = lane >> 4;
    const int swz = (hi ^ (fr & 3)) * 8;   // de-swizzle on fragment read

    for (int k0 = 0; k0 < K; k0 += 32) {
        #pragma unroll
        for (int j2 = 0; j2 < 2; ++j2) {
            const int seg = seg0 + j2;
            async_copy16(Abase + (size_t)(seg * 16) * K + k0, sA + seg * 512);
            async_copy16(Bbase + (size_t)(seg * 16) * K + k0, sB + seg * 512);
        }
        __syncthreads();

        bf16x8 af[4], bfr[4];
        #pragma unroll
        for (int i = 0; i < 4; ++i)
            af[i] = *(const bf16x8*)(sA + (wr + i * 16 + fr) * 32 + swz);
        #pragma unroll
        for (int j = 0; j < 4; ++j)
            bfr[j] = *(const bf16x8*)(sB + (wc + j * 16 + fr) * 32 + swz);

        #pragma unroll
        for (int i = 0; i < 4; ++i)
            #pragma unroll
            for (int j = 0; j < 4; ++j)
                acc[i][j] = __builtin_amdgcn_mfma_f32_16x16x32_bf16(af[i], bfr[j], acc[i][j], 0, 0, 0);
        __syncthreads();
    }

    // epilogue: C/D layout col=lane&15, row=(lane>>4)*4+reg  [m89-verified]
    #pragma unroll
    for (int j = 0; j < 4; ++j) {
        const int gc = col0 + wc + j * 16 + fr;
        float cb = 0.f;
        if constexpr (BIAS_MODE == 0) cb = bias[gc];
        if constexpr (BIAS_MODE == 2) cb = bias[gc] + bias2[gc];
        #pragma unroll
        for (int i = 0; i < 4; ++i) {
            const int lr0 = wr + i * 16 + hi * 4;
            #pragma unroll
            for (int r = 0; r < 4; ++r) {
                float v = acc[i][j][r];
                if constexpr (BIAS_MODE == 1)
                    v += stb[((lr0 + r) >> 3) * 132 + wc + j * 16 + fr];
                else
                    v += cb;
                C[(size_t)(row0 + lr0 + r) * N + gc] = (CT)v;
            }
        }
    }
}

// ---- fused attention + out-projection ----
// block: 32 rows of qkv -> attention -> a-tile (LDS) -> a @ W_out^T + b_out
__global__ __launch_bounds__(256, 2)
void attn_out(const bf16_t* __restrict__ qkv, const bf16_t* __restrict__ Wo,
              const float* __restrict__ bias, float* __restrict__ C)
{
    __shared__ __align__(16) bf16_t sa[32 * 512];   // swizzled a-tile (full K)
    __shared__ __align__(16) bf16_t sB[512 * 32];   // W_out k-slice (attn kv scratch first)

    const int tid  = threadIdx.x;
    const int wave = tid >> 6;
    const int lane = tid & 63;
    const int row0 = blockIdx.x * 32;

    // ---- attention: wave w handles local rows w*8 .. w*8+7 ----
    bf16_t* kv = sB + wave * 1024;   // 512 k + 512 v
    for (int rr = 0; rr < 8; ++rr) {
        const int r = wave * 8 + rr;
        const bf16_t* base = qkv + (size_t)(row0 + r) * 1536;
        bf16x8 q8 = *(const bf16x8*)(base + lane * 8);
        bf16x8 k8 = *(const bf16x8*)(base + 512 + lane * 8);
        bf16x8 v8 = *(const bf16x8*)(base + 1024 + lane * 8);
        *(bf16x8*)(kv + lane * 8)       = k8;
        *(bf16x8*)(kv + 512 + lane * 8) = v8;

        float q[8];
        #pragma unroll
        for (int e = 0; e < 8; ++e) q[e] = (float)q8[e];

        const int s8 = (lane & 7) * 8;
        float S[8];
        #pragma unroll
        for (int j = 0; j < 8; ++j) {
            bf16x8 kj = *(const bf16x8*)(kv + j * 64 + s8);
            float p = 0.f;
            #pragma unroll
            for (int e = 0; e < 8; ++e) p += q[e] * (float)kj[e];
            p += __shfl_xor(p, 1);
            p += __shfl_xor(p, 2);
            p += __shfl_xor(p, 4);
            S[j] = p * 0.125f;   // (64^-0.25)^2 = 1/8
        }
        float m = S[0];
        #pragma unroll
        for (int j = 1; j < 8; ++j) m = fmaxf(m, S[j]);
        float sum = 0.f;
        #pragma unroll
        for (int j = 0; j < 8; ++j) { S[j] = __expf(S[j] - m); sum += S[j]; }
        const float inv = 1.f / sum;

        float o[8] = {0.f, 0.f, 0.f, 0.f, 0.f, 0.f, 0.f, 0.f};
        #pragma unroll
        for (int j = 0; j < 8; ++j) {
            const float pj = S[j] * inv;
            bf16x8 vj = *(const bf16x8*)(kv + 512 + j * 64 + s8);
            #pragma unroll
            for (int e = 0; e < 8; ++e) o[e] += pj * (float)vj[e];
        }
        bf16x8 o8;
        #pragma unroll
        for (int e = 0; e < 8; ++e) o8[e] = (__bf16)o[e];
        // swizzled store: chunk (lane) XORed by (row&7) in its low 3 bits
        *(bf16x8*)(sa + r * 512 + ((lane ^ (r & 7)) * 8)) = o8;
    }
    __syncthreads();

    // ---- GEMM: C[32,512] = a[32,512] @ Wo[512,512]^T ----
    const int wc = wave << 7;
    const int fr = lane & 15;
    const int hi = lane >> 4;
    const int srow  = lane >> 2;
    const int schnk = (((lane & 3) ^ (srow & 3)) * 8);
    const int swzB  = (hi ^ (fr & 3)) * 8;
    const int swzA  = fr & 7;

    f32x4 acc[2][8];
    #pragma unroll
    for (int i = 0; i < 2; ++i)
        #pragma unroll
        for (int j = 0; j < 8; ++j)
            acc[i][j] = (f32x4){0.f, 0.f, 0.f, 0.f};

    for (int k0 = 0; k0 < 512; k0 += 32) {
        // wave stages its own 128 rows of Wo: 8 rounds of 16 rows
        #pragma unroll
        for (int c = 0; c < 8; ++c) {
            const int rowb = wc + c * 16;
            async_copy16(Wo + (size_t)(rowb + srow) * 512 + k0 + schnk,
                         sB + (size_t)rowb * 32);
        }
        __syncthreads();

        bf16x8 af[2], bfr[8];
        const int qc = (k0 >> 3) + hi;   // logical 8-elem chunk index in K
        #pragma unroll
        for (int i = 0; i < 2; ++i)
            af[i] = *(const bf16x8*)(sa + (i * 16 + fr) * 512 + ((qc ^ swzA) * 8));
        #pragma unroll
        for (int j = 0; j < 8; ++j)
            bfr[j] = *(const bf16x8*)(sB + (wc + j * 16 + fr) * 32 + swzB);

        #pragma unroll
        for (int i = 0; i < 2; ++i)
            #pragma unroll
            for (int j = 0; j < 8; ++j)
                acc[i][j] = __builtin_amdgcn_mfma_f32_16x16x32_bf16(af[i], bfr[j], acc[i][j], 0, 0, 0);
        __syncthreads();
    }

    #pragma unroll
    for (int j = 0; j < 8; ++j) {
        const int gc = wc + j * 16 + fr;
        const float cb = bias[gc];
        #pragma unroll
        for (int i = 0; i < 2; ++i) {
            const int gr0 = row0 + i * 16 + hi * 4;
            #pragma unroll
            for (int r = 0; r < 4; ++r)
                C[(size_t)(gr0 + r) * 512 + gc] = acc[i][j][r] + cb;
        }
    }
}

extern "C" void kernel_launch(void* const* d_in, const int* in_sizes, int n_in,
                              void* d_out, int out_size, void* d_ws, size_t ws_size,
                              hipStream_t stream)
{
    const float* x      = (const float*)d_in[0];
    const float* t      = (const float*)d_in[1];
    const float* W_down = (const float*)d_in[2];
    const float* b_down = (const float*)d_in[3];
    const float* W_t    = (const float*)d_in[4];
    const float* b_t    = (const float*)d_in[5];
    const float* W_qkv  = (const float*)d_in[6];
    const float* b_qkv  = (const float*)d_in[7];
    const float* W_out  = (const float*)d_in[8];
    const float* b_out  = (const float*)d_in[9];
    float* out = (float*)d_out;

    char* p = (char*)d_ws;
    bf16_t* xb     = (bf16_t*)(p);                  // 134,217,728
    bf16_t* qkvm   = (bf16_t*)(p + 134217728);      // 201,326,592
    float*  tbias2 = (float*) (p + 335544320);      //  50,331,648 (8192x1536 f32)
    bf16_t* tin    = (bf16_t*)(p + 385875968);      //   8,388,608
    bf16_t* tb     = (bf16_t*)(p + 394264576);      //   8,388,608
    bf16_t* wdT    = (bf16_t*)(p + 402653184);      //   1,048,576 (1024x512)
    bf16_t* wt     = (bf16_t*)(p + 403701760);      //     524,288
    bf16_t* wq     = (bf16_t*)(p + 404226048);      //   1,572,864
    bf16_t* wo     = (bf16_t*)(p + 405798912);      //     524,288
    bf16_t* wf     = (bf16_t*)(p + 406323200);      //   3,145,728 (1536x1024)

    // 1) conversions
    cvt_f32_bf16<<<32768, 256, 0, stream>>>(x, xb, (long)N_ROWS * IN_CH / 8);
    cvt_multi<<<2688, 256, 0, stream>>>(
        t,     tin, (long)BS_ * T_DIM / 8,
        W_qkv, wq,  (long)3 * OUT_CH * OUT_CH / 8,
        W_t,   wt,  (long)OUT_CH * T_DIM / 8,
        W_out, wo,  (long)OUT_CH * OUT_CH / 8);
    transpose_cvt<<<dim3(16, 8), 256, 0, stream>>>(W_down, wdT);

    // 2) Wf = W_qkv @ W_down  [1536,1024]
    gemm_bt<3, bf16_t><<<dim3(8, 12), 256, 0, stream>>>(
        wq, wdT, wf, nullptr, nullptr, 3 * OUT_CH, IN_CH, OUT_CH);

    // 3) tb = t @ W_t^T + b_t + b_down  [8192,512] bf16
    gemm_bt<2, bf16_t><<<dim3(4, 64), 256, 0, stream>>>(
        tin, wt, tb, b_t, b_down, BS_, OUT_CH, T_DIM);

    // 4) tbias2 = tb @ W_qkv^T + b_qkv  [8192,1536] f32
    gemm_bt<0, float><<<dim3(12, 64), 256, 0, stream>>>(
        tb, wq, tbias2, b_qkv, nullptr, BS_, 3 * OUT_CH, OUT_CH);

    // 5) qkv = x @ Wf^T + tbias2[row>>3]  [65536,1536] bf16
    gemm_bt<1, bf16_t><<<dim3(12, 512), 256, 0, stream>>>(
        xb, wf, qkvm, nullptr, tbias2, N_ROWS, 3 * OUT_CH, IN_CH);

    // 6) fused attention + out-projection
    attn_out<<<2048, 256, 0, stream>>>(qkvm, wo, b_out, out);
}